// Round 6
// baseline (55.098 us; speedup 1.0000x reference)
//
#include <hip/hip_runtime.h>
#include <math.h>

#define BB 4
#define ND 256
#define NE 512
#define CC 256

#define K2E 2.8853900817779268f   // 2 * log2(e): exp2(K2E*x) = e^{2x}
#define LOG2E 1.4426950408889634f
#define LN2 0.6931471805599453f

// ---------------------------------------------------------------------------
// Projection GEMM + exp epilogue (unchanged).
//   enc rows:  Et[b][c][e] = exp2(K2E*clamp(x_enc@w1^T, +-13))  TRANSPOSED
//   dec rows:  Dexp[n][c]  = exp2(K2E*clamp(x_dec@w2^T, +-13))  row-major
// ---------------------------------------------------------------------------
__global__ __launch_bounds__(256) void proj_kernel(
    const float* __restrict__ xdec, const float* __restrict__ xenc,
    const float* __restrict__ w1,   const float* __restrict__ w2,
    float* __restrict__ Et, float* __restrict__ Dexp)
{
    __shared__ float Xs[16][36];
    __shared__ float Ws[16][68];

    const int row0 = blockIdx.x * 32;
    const int col0 = blockIdx.y * 64;
    const bool is_enc = (row0 < BB * NE);

    const float* X = is_enc ? xenc : xdec;
    const float* W = is_enc ? w1   : w2;
    const int xrow0 = is_enc ? row0 : (row0 - BB * NE);

    const int tid = threadIdx.x;
    const int xr = tid >> 3, xk = (tid & 7) * 2;
    const int wc = tid >> 2, wk = (tid & 3) * 4;
    const int ty = tid >> 5;
    const int tx = tid & 31;

    float acc[4][2] = {};

    for (int k0 = 0; k0 < CC; k0 += 16) {
        float2 xv = *(const float2*)&X[(xrow0 + xr) * CC + k0 + xk];
        float4 wv = *(const float4*)&W[(col0 + wc) * CC + k0 + wk];
        __syncthreads();
        Xs[xk][xr] = xv.x; Xs[xk + 1][xr] = xv.y;
        Ws[wk][wc] = wv.x; Ws[wk + 1][wc] = wv.y;
        Ws[wk + 2][wc] = wv.z; Ws[wk + 3][wc] = wv.w;
        __syncthreads();
#pragma unroll
        for (int k = 0; k < 16; ++k) {
            float4 a = *(const float4*)&Xs[k][ty * 4];
            float2 b = *(const float2*)&Ws[k][tx * 2];
            acc[0][0] += a.x * b.x; acc[0][1] += a.x * b.y;
            acc[1][0] += a.y * b.x; acc[1][1] += a.y * b.y;
            acc[2][0] += a.z * b.x; acc[2][1] += a.z * b.y;
            acc[3][0] += a.w * b.x; acc[3][1] += a.w * b.y;
        }
    }

    float ex[4][2];
#pragma unroll
    for (int i = 0; i < 4; ++i)
#pragma unroll
        for (int j = 0; j < 2; ++j)
            ex[i][j] = __builtin_amdgcn_exp2f(
                K2E * fminf(fmaxf(acc[i][j], -13.f), 13.f));

    if (is_enc) {
        const int b  = row0 >> 9;
        const int e0 = (row0 & 511) + ty * 4;
#pragma unroll
        for (int j = 0; j < 2; ++j) {
            float4 o = make_float4(ex[0][j], ex[1][j], ex[2][j], ex[3][j]);
            *(float4*)&Et[((size_t)b * CC + col0 + tx * 2 + j) * NE + e0] = o;
        }
    } else {
#pragma unroll
        for (int i = 0; i < 4; ++i) {
            float2 o = make_float2(ex[i][0], ex[i][1]);
            *(float2*)&Dexp[(size_t)(xrow0 + ty * 4 + i) * CC + col0 + tx * 2] = o;
        }
    }
}

// ---------------------------------------------------------------------------
// Fused tanh-dot + log_softmax, paired-division form, NO LDS in hot loop:
// v and Dexp are read with wave-uniform indices -> compiler scalarizes to
// s_load (SMEM pipe), freeing the LDS/VALU issue slots that dominated R5.
// ---------------------------------------------------------------------------
__global__ __launch_bounds__(512) void attn_kernel(
    const float* __restrict__ Et, const float* __restrict__ Dexp,
    const float* __restrict__ v, float* __restrict__ out)
{
    __shared__ float prod[4][NE];

    const int blk = blockIdx.x;       // 0..255
    const int b   = blk >> 6;
    const int n0  = (blk & 63) * 4;
    const int tid = threadIdx.x;      // == e, 0..511

    const float* __restrict__ D0 = Dexp + (size_t)(b * ND + n0 + 0) * CC;
    const float* __restrict__ D1 = Dexp + (size_t)(b * ND + n0 + 1) * CC;
    const float* __restrict__ D2 = Dexp + (size_t)(b * ND + n0 + 2) * CC;
    const float* __restrict__ D3 = Dexp + (size_t)(b * ND + n0 + 3) * CC;
    const float* Ecol = Et + (size_t)b * CC * NE + tid;

    float a0 = 0.f, a1 = 0.f, a2 = 0.f, a3 = 0.f;
    float Ev0[16], Ev1[16];

// one paired step: elements (c,c+1) for one accumulator row
#define PAIR(ACC, E0, E1, V0, V1, Dx0, Dx1) do {                             \
        const float _d0 = fmaf((E0), (Dx0), 1.0f);                           \
        const float _d1 = fmaf((E1), (Dx1), 1.0f);                           \
        const float _num = fmaf((V1), _d0, (V0) * _d1);                      \
        ACC = fmaf(_num, __builtin_amdgcn_rcpf(_d0 * _d1), ACC);             \
    } while (0)

#define PROCESS(EV, CB) do {                                                 \
        _Pragma("unroll")                                                    \
        for (int cs = 0; cs < 16; cs += 4) {                                 \
            float4 vq = *(const float4*)&v[(CB) + cs];                       \
            float4 q0 = *(const float4*)&D0[(CB) + cs];                      \
            float4 q1 = *(const float4*)&D1[(CB) + cs];                      \
            float4 q2 = *(const float4*)&D2[(CB) + cs];                      \
            float4 q3 = *(const float4*)&D3[(CB) + cs];                      \
            PAIR(a0, EV[cs + 0], EV[cs + 1], vq.x, vq.y, q0.x, q0.y);        \
            PAIR(a1, EV[cs + 0], EV[cs + 1], vq.x, vq.y, q1.x, q1.y);        \
            PAIR(a2, EV[cs + 0], EV[cs + 1], vq.x, vq.y, q2.x, q2.y);        \
            PAIR(a3, EV[cs + 0], EV[cs + 1], vq.x, vq.y, q3.x, q3.y);        \
            PAIR(a0, EV[cs + 2], EV[cs + 3], vq.z, vq.w, q0.z, q0.w);        \
            PAIR(a1, EV[cs + 2], EV[cs + 3], vq.z, vq.w, q1.z, q1.w);        \
            PAIR(a2, EV[cs + 2], EV[cs + 3], vq.z, vq.w, q2.z, q2.w);        \
            PAIR(a3, EV[cs + 2], EV[cs + 3], vq.z, vq.w, q3.z, q3.w);        \
        }                                                                    \
    } while (0)

#pragma unroll
    for (int j = 0; j < 16; ++j) Ev0[j] = Ecol[(size_t)j * NE];

    for (int c0 = 0; c0 < CC; c0 += 32) {
#pragma unroll
        for (int j = 0; j < 16; ++j) Ev1[j] = Ecol[(size_t)(c0 + 16 + j) * NE];
        PROCESS(Ev0, c0);
        if (c0 + 32 < CC) {
#pragma unroll
            for (int j = 0; j < 16; ++j) Ev0[j] = Ecol[(size_t)(c0 + 32 + j) * NE];
        }
        PROCESS(Ev1, c0 + 16);
    }
#undef PROCESS
#undef PAIR

    prod[0][tid] = -2.0f * a0;
    prod[1][tid] = -2.0f * a1;
    prod[2][tid] = -2.0f * a2;
    prod[3][tid] = -2.0f * a3;
    __syncthreads();

    // log_softmax: wave w (w<4) handles decoder row n0+w
    const int w    = tid >> 6;
    const int lane = tid & 63;
    if (w < 4) {
        float p[8];
#pragma unroll
        for (int i = 0; i < 8; ++i) p[i] = prod[w][lane + 64 * i];
        float m = p[0];
#pragma unroll
        for (int i = 1; i < 8; ++i) m = fmaxf(m, p[i]);
#pragma unroll
        for (int off = 1; off < 64; off <<= 1) m = fmaxf(m, __shfl_xor(m, off));
        float s = 0.f;
#pragma unroll
        for (int i = 0; i < 8; ++i) s += __builtin_amdgcn_exp2f((p[i] - m) * LOG2E);
#pragma unroll
        for (int off = 1; off < 64; off <<= 1) s += __shfl_xor(s, off);
        const float lse = m + __builtin_amdgcn_logf(s) * LN2;

        float* o = out + (size_t)(b * ND + n0 + w) * NE;
#pragma unroll
        for (int i = 0; i < 8; ++i) o[lane + 64 * i] = p[i] - lse;
    }
}

// ---------------------------------------------------------------------------
extern "C" void kernel_launch(void* const* d_in, const int* in_sizes, int n_in,
                              void* d_out, int out_size, void* d_ws, size_t ws_size,
                              hipStream_t stream) {
    const float* xdec = (const float*)d_in[0];   // (4,256,256)
    const float* xenc = (const float*)d_in[1];   // (4,512,256)
    const float* w1   = (const float*)d_in[2];   // (256,256)
    const float* w2   = (const float*)d_in[3];   // (256,256)
    const float* v    = (const float*)d_in[4];   // (1,256)
    float* out = (float*)d_out;                  // (4,256,512)

    float* Et   = (float*)d_ws;                  // [4][256][512] f32 = 2 MB (transposed)
    float* Dexp = Et + (size_t)BB * CC * NE;     // [1024][256] f32 = 1 MB

    dim3 gproj(96, 4);
    proj_kernel<<<gproj, 256, 0, stream>>>(xdec, xenc, w1, w2, Et, Dexp);
    // MEASUREMENT ROUND: attn launched TWICE (idempotent — writes identical
    // output). dur_us = proj + 2*attn + ovh lets us solve for attn's share,
    // which the fill-dominated top-5 profile has been hiding. Remove next round.
    attn_kernel<<<(BB * ND) / 4, 512, 0, stream>>>(Et, Dexp, v, out);
    attn_kernel<<<(BB * ND) / 4, 512, 0, stream>>>(Et, Dexp, v, out);
}

// Round 7
// 47.252 us; speedup vs baseline: 1.1660x; 1.1660x over previous
//
#include <hip/hip_runtime.h>
#include <math.h>

#define BB 4
#define ND 256
#define NE 512
#define CC 256

#define K2E 2.8853900817779268f   // 2 * log2(e): exp2(K2E*x) = e^{2x}
#define LOG2E 1.4426950408889634f
#define LN2 0.6931471805599453f

// ---------------------------------------------------------------------------
// Projection GEMM + exp epilogue (unchanged).
//   enc rows:  Et[b][c][e] = exp2(K2E*clamp(x_enc@w1^T, +-13))  TRANSPOSED
//   dec rows:  Dexp[n][c]  = exp2(K2E*clamp(x_dec@w2^T, +-13))  row-major
// ---------------------------------------------------------------------------
__global__ __launch_bounds__(256) void proj_kernel(
    const float* __restrict__ xdec, const float* __restrict__ xenc,
    const float* __restrict__ w1,   const float* __restrict__ w2,
    float* __restrict__ Et, float* __restrict__ Dexp)
{
    __shared__ float Xs[16][36];
    __shared__ float Ws[16][68];

    const int row0 = blockIdx.x * 32;
    const int col0 = blockIdx.y * 64;
    const bool is_enc = (row0 < BB * NE);

    const float* X = is_enc ? xenc : xdec;
    const float* W = is_enc ? w1   : w2;
    const int xrow0 = is_enc ? row0 : (row0 - BB * NE);

    const int tid = threadIdx.x;
    const int xr = tid >> 3, xk = (tid & 7) * 2;
    const int wc = tid >> 2, wk = (tid & 3) * 4;
    const int ty = tid >> 5;
    const int tx = tid & 31;

    float acc[4][2] = {};

    for (int k0 = 0; k0 < CC; k0 += 16) {
        float2 xv = *(const float2*)&X[(xrow0 + xr) * CC + k0 + xk];
        float4 wv = *(const float4*)&W[(col0 + wc) * CC + k0 + wk];
        __syncthreads();
        Xs[xk][xr] = xv.x; Xs[xk + 1][xr] = xv.y;
        Ws[wk][wc] = wv.x; Ws[wk + 1][wc] = wv.y;
        Ws[wk + 2][wc] = wv.z; Ws[wk + 3][wc] = wv.w;
        __syncthreads();
#pragma unroll
        for (int k = 0; k < 16; ++k) {
            float4 a = *(const float4*)&Xs[k][ty * 4];
            float2 b = *(const float2*)&Ws[k][tx * 2];
            acc[0][0] += a.x * b.x; acc[0][1] += a.x * b.y;
            acc[1][0] += a.y * b.x; acc[1][1] += a.y * b.y;
            acc[2][0] += a.z * b.x; acc[2][1] += a.z * b.y;
            acc[3][0] += a.w * b.x; acc[3][1] += a.w * b.y;
        }
    }

    float ex[4][2];
#pragma unroll
    for (int i = 0; i < 4; ++i)
#pragma unroll
        for (int j = 0; j < 2; ++j)
            ex[i][j] = __builtin_amdgcn_exp2f(
                K2E * fminf(fmaxf(acc[i][j], -13.f), 13.f));

    if (is_enc) {
        const int b  = row0 >> 9;
        const int e0 = (row0 & 511) + ty * 4;
#pragma unroll
        for (int j = 0; j < 2; ++j) {
            float4 o = make_float4(ex[0][j], ex[1][j], ex[2][j], ex[3][j]);
            *(float4*)&Et[((size_t)b * CC + col0 + tx * 2 + j) * NE + e0] = o;
        }
    } else {
#pragma unroll
        for (int i = 0; i < 4; ++i) {
            float2 o = make_float2(ex[i][0], ex[i][1]);
            *(float2*)&Dexp[(size_t)(xrow0 + ty * 4 + i) * CC + col0 + tx * 2] = o;
        }
    }
}

// ---------------------------------------------------------------------------
// Fused tanh-dot + log_softmax, paired-division form.
//   v0/d0 + v1/d1 = (v0*d1 + v1*d0) / (d0*d1),  d = fma(E, D, 1)
// 2 decoder rows per 512-thread block -> 512 blocks (2 blocks/CU, better
// latency hiding). E and D/v BOTH ping-pong prefetched 16 c ahead in
// registers so no load is consumed in the chunk that issues it.
// ---------------------------------------------------------------------------
__global__ __launch_bounds__(512) void attn_kernel(
    const float* __restrict__ Et, const float* __restrict__ Dexp,
    const float* __restrict__ v, float* __restrict__ out)
{
    __shared__ float prod[2][NE];

    const int blk = blockIdx.x;       // 0..511
    const int b   = blk >> 7;
    const int n0  = (blk & 127) * 2;
    const int tid = threadIdx.x;      // == e, 0..511

    const float* __restrict__ D0 = Dexp + (size_t)(b * ND + n0 + 0) * CC;
    const float* __restrict__ D1 = Dexp + (size_t)(b * ND + n0 + 1) * CC;
    const float* Ecol = Et + (size_t)b * CC * NE + tid;

    float a0 = 0.f, a1 = 0.f;
    float Ev0[16], Ev1[16];
    float4 vqA[4], q0A[4], q1A[4];
    float4 vqB[4], q0B[4], q1B[4];

#define PAIR(ACC, E0, E1, V0, V1, Dx0, Dx1) do {                             \
        const float _d0 = fmaf((E0), (Dx0), 1.0f);                           \
        const float _d1 = fmaf((E1), (Dx1), 1.0f);                           \
        const float _num = fmaf((V1), _d0, (V0) * _d1);                      \
        ACC = fmaf(_num, __builtin_amdgcn_rcpf(_d0 * _d1), ACC);             \
    } while (0)

#define LOADE(EV, CB) do {                                                   \
        _Pragma("unroll")                                                    \
        for (int j = 0; j < 16; ++j) EV[j] = Ecol[(size_t)((CB) + j) * NE];  \
    } while (0)

#define LOADDV(VQ, Q0, Q1, CB) do {                                          \
        _Pragma("unroll")                                                    \
        for (int i = 0; i < 4; ++i) {                                        \
            VQ[i] = *(const float4*)&v [(CB) + 4 * i];                       \
            Q0[i] = *(const float4*)&D0[(CB) + 4 * i];                       \
            Q1[i] = *(const float4*)&D1[(CB) + 4 * i];                       \
        }                                                                    \
    } while (0)

#define PROCESS(EV, VQ, Q0, Q1) do {                                         \
        _Pragma("unroll")                                                    \
        for (int i = 0; i < 4; ++i) {                                        \
            PAIR(a0, EV[4*i+0], EV[4*i+1], VQ[i].x, VQ[i].y, Q0[i].x, Q0[i].y); \
            PAIR(a1, EV[4*i+0], EV[4*i+1], VQ[i].x, VQ[i].y, Q1[i].x, Q1[i].y); \
            PAIR(a0, EV[4*i+2], EV[4*i+3], VQ[i].z, VQ[i].w, Q0[i].z, Q0[i].w); \
            PAIR(a1, EV[4*i+2], EV[4*i+3], VQ[i].z, VQ[i].w, Q1[i].z, Q1[i].w); \
        }                                                                    \
    } while (0)

    LOADE(Ev0, 0);
    LOADDV(vqA, q0A, q1A, 0);

    for (int c0 = 0; c0 < CC; c0 += 32) {
        LOADE(Ev1, c0 + 16);
        LOADDV(vqB, q0B, q1B, c0 + 16);
        PROCESS(Ev0, vqA, q0A, q1A);
        if (c0 + 32 < CC) {
            LOADE(Ev0, c0 + 32);
            LOADDV(vqA, q0A, q1A, c0 + 32);
        }
        PROCESS(Ev1, vqB, q0B, q1B);
    }
#undef PROCESS
#undef LOADDV
#undef LOADE
#undef PAIR

    prod[0][tid] = -2.0f * a0;
    prod[1][tid] = -2.0f * a1;
    __syncthreads();

    // log_softmax: wave w (w<2) handles decoder row n0+w
    const int w    = tid >> 6;
    const int lane = tid & 63;
    if (w < 2) {
        float p[8];
#pragma unroll
        for (int i = 0; i < 8; ++i) p[i] = prod[w][lane + 64 * i];
        float m = p[0];
#pragma unroll
        for (int i = 1; i < 8; ++i) m = fmaxf(m, p[i]);
#pragma unroll
        for (int off = 1; off < 64; off <<= 1) m = fmaxf(m, __shfl_xor(m, off));
        float s = 0.f;
#pragma unroll
        for (int i = 0; i < 8; ++i) s += __builtin_amdgcn_exp2f((p[i] - m) * LOG2E);
#pragma unroll
        for (int off = 1; off < 64; off <<= 1) s += __shfl_xor(s, off);
        const float lse = m + __builtin_amdgcn_logf(s) * LN2;

        float* o = out + (size_t)(b * ND + n0 + w) * NE;
#pragma unroll
        for (int i = 0; i < 8; ++i) o[lane + 64 * i] = p[i] - lse;
    }
}

// ---------------------------------------------------------------------------
extern "C" void kernel_launch(void* const* d_in, const int* in_sizes, int n_in,
                              void* d_out, int out_size, void* d_ws, size_t ws_size,
                              hipStream_t stream) {
    const float* xdec = (const float*)d_in[0];   // (4,256,256)
    const float* xenc = (const float*)d_in[1];   // (4,512,256)
    const float* w1   = (const float*)d_in[2];   // (256,256)
    const float* w2   = (const float*)d_in[3];   // (256,256)
    const float* v    = (const float*)d_in[4];   // (1,256)
    float* out = (float*)d_out;                  // (4,256,512)

    float* Et   = (float*)d_ws;                  // [4][256][512] f32 = 2 MB (transposed)
    float* Dexp = Et + (size_t)BB * CC * NE;     // [1024][256] f32 = 1 MB

    dim3 gproj(96, 4);
    proj_kernel<<<gproj, 256, 0, stream>>>(xdec, xenc, w1, w2, Et, Dexp);
    attn_kernel<<<(BB * ND) / 2, 512, 0, stream>>>(Et, Dexp, v, out);
}

// Round 9
// 44.939 us; speedup vs baseline: 1.2261x; 1.0515x over previous
//
#include <hip/hip_runtime.h>
#include <math.h>

#define BB 4
#define ND 256
#define NE 512
#define CC 256

#define K2E 2.8853900817779268f   // 2 * log2(e): exp2(K2E*x) = e^{2x}
#define LOG2E 1.4426950408889634f
#define LN2 0.6931471805599453f

typedef unsigned int u32;
typedef unsigned short u16;

__device__ __forceinline__ u16 f2bf(float f) {   // RTNE float->bf16
    u32 u = __builtin_bit_cast(u32, f);
    u += 0x7fffu + ((u >> 16) & 1u);
    return (u16)(u >> 16);
}
__device__ __forceinline__ float bflo(u32 u) { return __builtin_bit_cast(float, u << 16); }
__device__ __forceinline__ float bfhi(u32 u) { return __builtin_bit_cast(float, u & 0xffff0000u); }

// ---------------------------------------------------------------------------
// Projection GEMM + exp epilogue.
//   enc rows:  Et[b][c][e] = bf16(exp2(K2E*clamp(x_enc@w1^T,+-13)))  TRANSPOSED, bf16
//   dec rows:  Dexp[n][c]  = exp2(K2E*clamp(x_dec@w2^T,+-13))        row-major, f32
// ---------------------------------------------------------------------------
__global__ __launch_bounds__(256) void proj_kernel(
    const float* __restrict__ xdec, const float* __restrict__ xenc,
    const float* __restrict__ w1,   const float* __restrict__ w2,
    u16* __restrict__ Et, float* __restrict__ Dexp)
{
    __shared__ float Xs[16][36];
    __shared__ float Ws[16][68];

    const int row0 = blockIdx.x * 32;
    const int col0 = blockIdx.y * 64;
    const bool is_enc = (row0 < BB * NE);

    const float* X = is_enc ? xenc : xdec;
    const float* W = is_enc ? w1   : w2;
    const int xrow0 = is_enc ? row0 : (row0 - BB * NE);

    const int tid = threadIdx.x;
    const int xr = tid >> 3, xk = (tid & 7) * 2;
    const int wc = tid >> 2, wk = (tid & 3) * 4;
    const int ty = tid >> 5;
    const int tx = tid & 31;

    float acc[4][2] = {};

    for (int k0 = 0; k0 < CC; k0 += 16) {
        float2 xv = *(const float2*)&X[(xrow0 + xr) * CC + k0 + xk];
        float4 wv = *(const float4*)&W[(col0 + wc) * CC + k0 + wk];
        __syncthreads();
        Xs[xk][xr] = xv.x; Xs[xk + 1][xr] = xv.y;
        Ws[wk][wc] = wv.x; Ws[wk + 1][wc] = wv.y;
        Ws[wk + 2][wc] = wv.z; Ws[wk + 3][wc] = wv.w;
        __syncthreads();
#pragma unroll
        for (int k = 0; k < 16; ++k) {
            float4 a = *(const float4*)&Xs[k][ty * 4];
            float2 b = *(const float2*)&Ws[k][tx * 2];
            acc[0][0] += a.x * b.x; acc[0][1] += a.x * b.y;
            acc[1][0] += a.y * b.x; acc[1][1] += a.y * b.y;
            acc[2][0] += a.z * b.x; acc[2][1] += a.z * b.y;
            acc[3][0] += a.w * b.x; acc[3][1] += a.w * b.y;
        }
    }

    float ex[4][2];
#pragma unroll
    for (int i = 0; i < 4; ++i)
#pragma unroll
        for (int j = 0; j < 2; ++j)
            ex[i][j] = __builtin_amdgcn_exp2f(
                K2E * fminf(fmaxf(acc[i][j], -13.f), 13.f));

    if (is_enc) {
        const int b  = row0 >> 9;
        const int e0 = (row0 & 511) + ty * 4;
#pragma unroll
        for (int j = 0; j < 2; ++j) {
            ushort4 o;
            o.x = f2bf(ex[0][j]); o.y = f2bf(ex[1][j]);
            o.z = f2bf(ex[2][j]); o.w = f2bf(ex[3][j]);
            *(ushort4*)&Et[((size_t)b * CC + col0 + tx * 2 + j) * NE + e0] = o;
        }
    } else {
#pragma unroll
        for (int i = 0; i < 4; ++i) {
            float2 o = make_float2(ex[i][0], ex[i][1]);
            *(float2*)&Dexp[(size_t)(xrow0 + ty * 4 + i) * CC + col0 + tx * 2] = o;
        }
    }
}

// ---------------------------------------------------------------------------
// Fused tanh-dot, paired-division, bf16 E, 8 rows x 256 e per block.
// Thread = 1 e-pair x 2 rows (4 accumulators). E dword = 2 bf16 elements.
// Writes RAW prod (no softmax) to ws; lsm_kernel finishes.
//   p'[n,e] = -2 * sum_c v_c / (1 + E*D)    (sum(v) shift cancels in lsm)
// ---------------------------------------------------------------------------
__global__ __launch_bounds__(512) void attn_kernel(
    const u16* __restrict__ Et, const float* __restrict__ Dexp,
    const float* __restrict__ v, float* __restrict__ prod)
{
    const int blk = blockIdx.x;        // 0..255
    const int b   = blk >> 6;
    const int sub = blk & 63;
    const int n0  = (sub >> 1) * 8;    // 32 row-groups of 8
    const int e0  = (sub & 1) * 256;   // 2 e-halves
    const int tid = threadIdx.x;
    const int ep  = tid & 127;         // e-pair index within half
    const int rg  = tid >> 7;          // 0..3: rows n0+2rg, n0+2rg+1 (wave-uniform)

    const float* __restrict__ D0 = Dexp + (size_t)(b * ND + n0 + 2 * rg) * CC;
    const float* __restrict__ D1 = D0 + CC;
    const u32* Ecol = (const u32*)Et + (size_t)b * CC * (NE / 2) + (e0 >> 1) + ep;

    float a00 = 0.f, a01 = 0.f, a10 = 0.f, a11 = 0.f;   // [row][e]
    u32 Eb0[16], Eb1[16];

#define PAIR(ACC, E0, E1, V0, V1, Dx0, Dx1) do {                             \
        const float _d0 = fmaf((E0), (Dx0), 1.0f);                           \
        const float _d1 = fmaf((E1), (Dx1), 1.0f);                           \
        const float _num = fmaf((V1), _d0, (V0) * _d1);                      \
        ACC = fmaf(_num, __builtin_amdgcn_rcpf(_d0 * _d1), ACC);             \
    } while (0)

#define LOADE(EB, CB) do {                                                   \
        _Pragma("unroll")                                                    \
        for (int j = 0; j < 16; ++j)                                         \
            EB[j] = Ecol[(size_t)((CB) + j) * (NE / 2)];                     \
    } while (0)

#define PROCESS(EB, CB) do {                                                 \
        _Pragma("unroll")                                                    \
        for (int i = 0; i < 4; ++i) {                                        \
            float4 vq = *(const float4*)&v [(CB) + 4 * i];                   \
            float4 p0 = *(const float4*)&D0[(CB) + 4 * i];                   \
            float4 p1 = *(const float4*)&D1[(CB) + 4 * i];                   \
            u32 ux = EB[4*i+0], uy = EB[4*i+1], uz = EB[4*i+2], uw = EB[4*i+3]; \
            PAIR(a00, bflo(ux), bflo(uy), vq.x, vq.y, p0.x, p0.y);           \
            PAIR(a01, bfhi(ux), bfhi(uy), vq.x, vq.y, p0.x, p0.y);           \
            PAIR(a10, bflo(ux), bflo(uy), vq.x, vq.y, p1.x, p1.y);           \
            PAIR(a11, bfhi(ux), bfhi(uy), vq.x, vq.y, p1.x, p1.y);           \
            PAIR(a00, bflo(uz), bflo(uw), vq.z, vq.w, p0.z, p0.w);           \
            PAIR(a01, bfhi(uz), bfhi(uw), vq.z, vq.w, p0.z, p0.w);           \
            PAIR(a10, bflo(uz), bflo(uw), vq.z, vq.w, p1.z, p1.w);           \
            PAIR(a11, bfhi(uz), bfhi(uw), vq.z, vq.w, p1.z, p1.w);           \
        }                                                                    \
    } while (0)

    LOADE(Eb0, 0);
    for (int c0 = 0; c0 < CC; c0 += 32) {
        LOADE(Eb1, c0 + 16);
        PROCESS(Eb0, c0);
        if (c0 + 32 < CC) LOADE(Eb0, c0 + 32);
        PROCESS(Eb1, c0 + 16);
    }
#undef PROCESS
#undef LOADE
#undef PAIR

    float* pr = prod + (size_t)(b * ND + n0 + 2 * rg) * NE + e0 + 2 * ep;
    *(float2*)pr        = make_float2(-2.0f * a00, -2.0f * a01);
    *(float2*)(pr + NE) = make_float2(-2.0f * a10, -2.0f * a11);
}

// ---------------------------------------------------------------------------
// log_softmax over e (512) per (b,n) row. One wave per row, 4 rows/block.
// ---------------------------------------------------------------------------
__global__ __launch_bounds__(256) void lsm_kernel(
    const float* __restrict__ prod, float* __restrict__ out)
{
    const int row  = blockIdx.x * 4 + (threadIdx.x >> 6);
    const int lane = threadIdx.x & 63;
    const float* p = prod + (size_t)row * NE;

    float x[8];
#pragma unroll
    for (int i = 0; i < 8; ++i) x[i] = p[lane + 64 * i];
    float m = x[0];
#pragma unroll
    for (int i = 1; i < 8; ++i) m = fmaxf(m, x[i]);
#pragma unroll
    for (int off = 1; off < 64; off <<= 1) m = fmaxf(m, __shfl_xor(m, off));
    float s = 0.f;
#pragma unroll
    for (int i = 0; i < 8; ++i) s += __builtin_amdgcn_exp2f((x[i] - m) * LOG2E);
#pragma unroll
    for (int off = 1; off < 64; off <<= 1) s += __shfl_xor(s, off);
    const float lse = m + __builtin_amdgcn_logf(s) * LN2;

    float* o = out + (size_t)row * NE;
#pragma unroll
    for (int i = 0; i < 8; ++i) o[lane + 64 * i] = x[i] - lse;
}

// ---------------------------------------------------------------------------
extern "C" void kernel_launch(void* const* d_in, const int* in_sizes, int n_in,
                              void* d_out, int out_size, void* d_ws, size_t ws_size,
                              hipStream_t stream) {
    const float* xdec = (const float*)d_in[0];   // (4,256,256)
    const float* xenc = (const float*)d_in[1];   // (4,512,256)
    const float* w1   = (const float*)d_in[2];   // (256,256)
    const float* w2   = (const float*)d_in[3];   // (256,256)
    const float* v    = (const float*)d_in[4];   // (1,256)
    float* out = (float*)d_out;                  // (4,256,512)

    char* ws = (char*)d_ws;
    u16*   Et   = (u16*)ws;                              // 4*256*512*2 = 1 MB (bf16, transposed)
    float* Dexp = (float*)(ws + (1u << 20));             // 1024*256*4  = 1 MB
    float* prod = (float*)(ws + (2u << 20));             // 1024*512*4  = 2 MB

    dim3 gproj(96, 4);
    proj_kernel<<<gproj, 256, 0, stream>>>(xdec, xenc, w1, w2, Et, Dexp);
    attn_kernel<<<256, 512, 0, stream>>>(Et, Dexp, v, prod);
    lsm_kernel<<<256, 256, 0, stream>>>(prod, out);
}

// Round 10
// 37.058 us; speedup vs baseline: 1.4868x; 1.2127x over previous
//
#include <hip/hip_runtime.h>
#include <math.h>

#define BB 4
#define ND 256
#define NE 512
#define CC 256

#define K2E 2.8853900817779268f   // 2 * log2(e): exp2(K2E*x) = e^{2x}
#define LOG2E 1.4426950408889634f
#define LN2 0.6931471805599453f

typedef unsigned int u32;
typedef unsigned short u16;

__device__ __forceinline__ u16 f2bf(float f) {   // RTNE float->bf16
    u32 u = __builtin_bit_cast(u32, f);
    u += 0x7fffu + ((u >> 16) & 1u);
    return (u16)(u >> 16);
}
__device__ __forceinline__ float bflo(u32 u) { return __builtin_bit_cast(float, u << 16); }
__device__ __forceinline__ float bfhi(u32 u) { return __builtin_bit_cast(float, u & 0xffff0000u); }

// ---------------------------------------------------------------------------
// Projection GEMM + exp epilogue.
//   enc rows:  Et2[b][cp][e] = u32( bf16(E[2cp][e]), bf16(E[2cp+1][e]) )
//              E = exp2(K2E*clamp(x_enc@w1^T, +-9)) -- COALESCED via LDS
//              transpose (the 2-4KB-strided scatter was ~30us, R3..R9).
//   dec rows:  Dexp[n][c] = exp2(K2E*clamp(x_dec@w2^T, +-9))  row-major f32
// ---------------------------------------------------------------------------
__global__ __launch_bounds__(256) void proj_kernel(
    const float* __restrict__ xdec, const float* __restrict__ xenc,
    const float* __restrict__ w1,   const float* __restrict__ w2,
    u32* __restrict__ Et2, float* __restrict__ Dexp)
{
    __shared__ float Xs[16][36];
    __shared__ float Ws[16][68];
    __shared__ u32   T[32][33];    // [cp_local][e_local] transpose staging

    const int row0 = blockIdx.x * 32;
    const int col0 = blockIdx.y * 64;
    const bool is_enc = (row0 < BB * NE);

    const float* X = is_enc ? xenc : xdec;
    const float* W = is_enc ? w1   : w2;
    const int xrow0 = is_enc ? row0 : (row0 - BB * NE);

    const int tid = threadIdx.x;
    const int xr = tid >> 3, xk = (tid & 7) * 2;
    const int wc = tid >> 2, wk = (tid & 3) * 4;
    const int ty = tid >> 5;        // 0..7  (4 rows each)
    const int tx = tid & 31;        // 0..31 (2 cols each)

    float acc[4][2] = {};

    for (int k0 = 0; k0 < CC; k0 += 16) {
        float2 xv = *(const float2*)&X[(xrow0 + xr) * CC + k0 + xk];
        float4 wv = *(const float4*)&W[(col0 + wc) * CC + k0 + wk];
        __syncthreads();
        Xs[xk][xr] = xv.x; Xs[xk + 1][xr] = xv.y;
        Ws[wk][wc] = wv.x; Ws[wk + 1][wc] = wv.y;
        Ws[wk + 2][wc] = wv.z; Ws[wk + 3][wc] = wv.w;
        __syncthreads();
#pragma unroll
        for (int k = 0; k < 16; ++k) {
            float4 a = *(const float4*)&Xs[k][ty * 4];
            float2 b = *(const float2*)&Ws[k][tx * 2];
            acc[0][0] += a.x * b.x; acc[0][1] += a.x * b.y;
            acc[1][0] += a.y * b.x; acc[1][1] += a.y * b.y;
            acc[2][0] += a.z * b.x; acc[2][1] += a.z * b.y;
            acc[3][0] += a.w * b.x; acc[3][1] += a.w * b.y;
        }
    }

    float ex[4][2];
#pragma unroll
    for (int i = 0; i < 4; ++i)
#pragma unroll
        for (int j = 0; j < 2; ++j)
            ex[i][j] = __builtin_amdgcn_exp2f(
                K2E * fminf(fmaxf(acc[i][j], -9.f), 9.f));

    if (is_enc) {
        // stage packed c-pair words into LDS, transposed
#pragma unroll
        for (int i = 0; i < 4; ++i)
            T[tx][ty * 4 + i] = (u32)f2bf(ex[i][0]) | ((u32)f2bf(ex[i][1]) << 16);
        __syncthreads();
        // coalesced write: 32 consecutive e per c-row
        const int b  = row0 >> 9;
        const int e0 = row0 & 511;
        const int el = tid & 31;
        const int c0 = tid >> 5;          // 0..7
#pragma unroll
        for (int i = 0; i < 4; ++i) {
            const int cpl = c0 + 8 * i;   // 0..31
            Et2[((size_t)b * (CC / 2) + (col0 >> 1) + cpl) * NE + e0 + el] = T[cpl][el];
        }
    } else {
#pragma unroll
        for (int i = 0; i < 4; ++i) {
            float2 o = make_float2(ex[i][0], ex[i][1]);
            *(float2*)&Dexp[(size_t)(xrow0 + ty * 4 + i) * CC + col0 + tx * 2] = o;
        }
    }
}

// ---------------------------------------------------------------------------
// Fused tanh-dot + log_softmax (R6 structure: the proven-8us shape).
//   p'[n,e] = -2 * sum_c v_c / (1 + E*D)    (sum(v) shift cancels in lsm)
//   paired division: v0/d0 + v1/d1 = (v0*d1 + v1*d0) / (d0*d1)
// 512 thr (tid = e), 2 decoder rows per block, 512 blocks (4 waves/SIMD).
// D/v addresses are block-uniform -> scalar (SMEM) loads. E: one dword =
// one c-pair for this lane's e; 8-word ping-pong prefetch.
// ---------------------------------------------------------------------------
__global__ __launch_bounds__(512) void attn_kernel(
    const u32* __restrict__ Et2, const float* __restrict__ Dexp,
    const float* __restrict__ v, float* __restrict__ out)
{
    __shared__ float prod[2][NE];

    const int blk = blockIdx.x;       // 0..511
    const int b   = blk >> 7;
    const int n0  = (blk & 127) * 2;
    const int tid = threadIdx.x;      // == e

    const float* __restrict__ D0 = Dexp + (size_t)(b * ND + n0) * CC;
    const float* __restrict__ D1 = D0 + CC;
    const u32* Ec = Et2 + (size_t)b * (CC / 2) * NE + tid;

    float a0 = 0.f, a1 = 0.f;
    u32 Eb0[8], Eb1[8];

#define PAIR(ACC, E0, E1, V0, V1, Dx0, Dx1) do {                             \
        const float _d0 = fmaf((E0), (Dx0), 1.0f);                           \
        const float _d1 = fmaf((E1), (Dx1), 1.0f);                           \
        const float _num = fmaf((V1), _d0, (V0) * _d1);                      \
        ACC = fmaf(_num, __builtin_amdgcn_rcpf(_d0 * _d1), ACC);             \
    } while (0)

#define LOADE(EB, CPB) do {                                                  \
        _Pragma("unroll")                                                    \
        for (int j = 0; j < 8; ++j)                                          \
            EB[j] = Ec[(size_t)((CPB) + j) * NE];                            \
    } while (0)

#define PROCESS(EB, CPB) do {                                                \
        _Pragma("unroll")                                                    \
        for (int j = 0; j < 8; ++j) {                                        \
            const int c = ((CPB) + j) * 2;                                   \
            const float vlo = v[c], vhi = v[c + 1];                          \
            const float e0f = bflo(EB[j]), e1f = bfhi(EB[j]);                \
            PAIR(a0, e0f, e1f, vlo, vhi, D0[c], D0[c + 1]);                  \
            PAIR(a1, e0f, e1f, vlo, vhi, D1[c], D1[c + 1]);                  \
        }                                                                    \
    } while (0)

    LOADE(Eb0, 0);
    for (int cp0 = 0; cp0 < CC / 2; cp0 += 16) {
        LOADE(Eb1, cp0 + 8);
        PROCESS(Eb0, cp0);
        if (cp0 + 16 < CC / 2) LOADE(Eb0, cp0 + 16);
        PROCESS(Eb1, cp0 + 8);
    }
#undef PROCESS
#undef LOADE
#undef PAIR

    prod[0][tid] = -2.0f * a0;
    prod[1][tid] = -2.0f * a1;
    __syncthreads();

    // log_softmax: wave w (w<2) handles decoder row n0+w
    const int w    = tid >> 6;
    const int lane = tid & 63;
    if (w < 2) {
        float p[8];
#pragma unroll
        for (int i = 0; i < 8; ++i) p[i] = prod[w][lane + 64 * i];
        float m = p[0];
#pragma unroll
        for (int i = 1; i < 8; ++i) m = fmaxf(m, p[i]);
#pragma unroll
        for (int off = 1; off < 64; off <<= 1) m = fmaxf(m, __shfl_xor(m, off));
        float s = 0.f;
#pragma unroll
        for (int i = 0; i < 8; ++i) s += __builtin_amdgcn_exp2f((p[i] - m) * LOG2E);
#pragma unroll
        for (int off = 1; off < 64; off <<= 1) s += __shfl_xor(s, off);
        const float lse = m + __builtin_amdgcn_logf(s) * LN2;

        float* o = out + (size_t)(b * ND + n0 + w) * NE;
#pragma unroll
        for (int i = 0; i < 8; ++i) o[lane + 64 * i] = p[i] - lse;
    }
}

// ---------------------------------------------------------------------------
extern "C" void kernel_launch(void* const* d_in, const int* in_sizes, int n_in,
                              void* d_out, int out_size, void* d_ws, size_t ws_size,
                              hipStream_t stream) {
    const float* xdec = (const float*)d_in[0];   // (4,256,256)
    const float* xenc = (const float*)d_in[1];   // (4,512,256)
    const float* w1   = (const float*)d_in[2];   // (256,256)
    const float* w2   = (const float*)d_in[3];   // (256,256)
    const float* v    = (const float*)d_in[4];   // (1,256)
    float* out = (float*)d_out;                  // (4,256,512)

    char* ws = (char*)d_ws;
    u32*   Et2  = (u32*)ws;                      // [4][128][512] u32 = 1 MB (bf16 c-pairs)
    float* Dexp = (float*)(ws + (1u << 20));     // [1024][256] f32 = 1 MB

    dim3 gproj(96, 4);
    proj_kernel<<<gproj, 256, 0, stream>>>(xdec, xenc, w1, w2, Et2, Dexp);
    attn_kernel<<<(BB * ND) / 2, 512, 0, stream>>>(Et2, Dexp, v, out);
}